// Round 1
// baseline (43.023 us; speedup 1.0000x reference)
//
#include <hip/hip_runtime.h>

// KL(p||q) for diagonal Gaussians, sigma_* are log-variances.
// out[b] = 0.5 * sum_d[ exp(sp-sq) + (mu_q-mu_p)^2*exp(-sq) + sq - sp - 1 ]
// B=16384, D=1024, f32 in/out. Memory-bound: 256 MB in / 64 KB out.

constexpr int D_DIM = 1024;

__global__ __launch_bounds__(256) void _KLD_MVNx2_kernel(
    const float* __restrict__ mu_q,
    const float* __restrict__ sigma_q,
    const float* __restrict__ mu_p,
    const float* __restrict__ sigma_p,
    float* __restrict__ out,
    int B)
{
    const int row = blockIdx.x;
    if (row >= B) return;
    const int tid = threadIdx.x;

    // Each of 256 threads handles 4 consecutive floats: 256*4 = 1024 = D.
    const size_t base = (size_t)row * D_DIM + (size_t)tid * 4;

    const float4 mq = *reinterpret_cast<const float4*>(mu_q + base);
    const float4 sq = *reinterpret_cast<const float4*>(sigma_q + base);
    const float4 mp = *reinterpret_cast<const float4*>(mu_p + base);
    const float4 sp = *reinterpret_cast<const float4*>(sigma_p + base);

    float s = 0.0f;
    {
        float d = mq.x - mp.x;
        s += __expf(sp.x - sq.x) + d * d * __expf(-sq.x) + (sq.x - sp.x);
    }
    {
        float d = mq.y - mp.y;
        s += __expf(sp.y - sq.y) + d * d * __expf(-sq.y) + (sq.y - sp.y);
    }
    {
        float d = mq.z - mp.z;
        s += __expf(sp.z - sq.z) + d * d * __expf(-sq.z) + (sq.z - sp.z);
    }
    {
        float d = mq.w - mp.w;
        s += __expf(sp.w - sq.w) + d * d * __expf(-sq.w) + (sq.w - sp.w);
    }
    s -= 4.0f;  // the "-1" per element, 4 elements per thread

    // Wave (64-lane) reduction.
    #pragma unroll
    for (int off = 32; off > 0; off >>= 1)
        s += __shfl_down(s, off);

    __shared__ float part[4];
    const int lane = tid & 63;
    const int wv   = tid >> 6;
    if (lane == 0) part[wv] = s;
    __syncthreads();

    if (tid == 0)
        out[row] = 0.5f * (part[0] + part[1] + part[2] + part[3]);
}

extern "C" void kernel_launch(void* const* d_in, const int* in_sizes, int n_in,
                              void* d_out, int out_size, void* d_ws, size_t ws_size,
                              hipStream_t stream) {
    const float* mu_q    = (const float*)d_in[0];
    const float* sigma_q = (const float*)d_in[1];
    const float* mu_p    = (const float*)d_in[2];
    const float* sigma_p = (const float*)d_in[3];
    float* out = (float*)d_out;

    const int B = out_size;  // 16384 rows
    _KLD_MVNx2_kernel<<<B, 256, 0, stream>>>(mu_q, sigma_q, mu_p, sigma_p, out, B);
}